// Round 12
// baseline (260.855 us; speedup 1.0000x reference)
//
#include <hip/hip_runtime.h>
#include <hip/hip_bf16.h>

// B=4, N=256, F=64, H=256, A=16, T=3.  BN=1024 rows.
// bf16 inputs (runtime-verified); adjacency int32.
// GEMMs: bf16 MFMA 16x16x32. Weights are EXACT in bf16 (inputs are bf16).
// Precision: activations h/Ehat stored as split hi/lo bf16 pairs along K,
// weights duplicated along K -> A_hi@B + A_lo@B in one MFMA GEMM (~fp32 acc).
// R1-R9: fusion + K-dedup + LDS pad + 256-blk gigru: 265us.
// R10: gh-fusion: 262.7. R11: graph<->XCD affinity: 257.6; FETCH 7.2->6.5MB
//     but gigru 48.5us. Theory survivors eliminated: volume(R7), rounds(R8),
//     CU-coverage(R9), epilogue(R10), XCD-RAW(R11).
// R12: latency-WINDOW model: per round only 10x16B loads, window = 1 round's
//     compute (~400cy) vs cold-line tail ~2000cy, 17 sequential stall points,
//     1 wave/SIMD no TLP. Fix: interleave phase1(gi,9rd) + phase2(gh,8rd)
//     into 9 super-rounds (separate LDS+accs, per-phase k-order unchanged ->
//     bitwise identical): 2x loads in flight, 2x compute per window, 9 stalls.

typedef unsigned short ushort_t;
typedef short bf8_t __attribute__((ext_vector_type(8)));
typedef float f4_t  __attribute__((ext_vector_type(4)));

#define BN_ROWS 1024

// ---- bf16 regions (USHORT offsets) ----
#define UB_NFB    0         // 65536   NF [1024][64] (exact)
#define UB_PW1T   65536     // 16384   preW1^T [256][64]
#define UB_PW2T   81920     // 65536   preW2^T [256][256]
#define UB_WCATT  147456    // 327680  Wcat^T [1280][256] (dedup: k&255)
#define UB_WGT    475136    // 442368  Wg^T [768][576] = [hi(288)|lo(288)]
#define UB_H2     917504    // 524288  h  [1024][512] hi|lo
#define UB_EHAT2  1441792   // 589824  Ehat [1024][576] = [Eh(288)|El(288)]
// end 2031616 ushorts = 1015808 floats

// ---- fp32 regions (FLOAT offsets) ----
#define F_PREB1   1015808   // 256
#define F_PREB2   1016064   // 256
#define F_BCAT    1016320   // 1280  [msg_b1 | 0 | gru_bhh]
#define F_BIH     1017600   // 768
#define F_ROW1    1018368   // 65536
#define F_ROB1    1083904   // 256
#define F_ROW2    1084160   // 4096
#define F_ROB2    1088256   // 16
#define F_H       1088272   // 262144
#define F_HCAT    1350416   // 524288 [hi_p | hj]
#define F_FLAG    2661136   // 1 int
#define F_GCNT    2661140   // 4 ints: per-graph readout arrival counters

// ---- convert index space ----
#define CVa 65536     // end NFB
#define CVb 81920     // end PW1T
#define CVc 147456    // end PW2T
#define CVd 475136    // end WCATT (1280*256)
#define CV_TOTAL 547600   // + 72464 fp32 tail
#define NCONV 1070        // convert blocks (2 elems/thread); wg blocks follow

__device__ __forceinline__ float bf2f(ushort_t u) {
    return __uint_as_float(((unsigned int)u) << 16);
}
__device__ __forceinline__ ushort_t f2b(float v) {
    __hip_bfloat16 b = __float2bfloat16(v);
    return *reinterpret_cast<ushort_t*>(&b);
}
__device__ __forceinline__ float relu(float v) { return v < 0.f ? 0.f : v; }  // NaN-propagating
__device__ __forceinline__ float ld(const void* p, int i, int isf32) {
    return isf32 ? ((const float*)p)[i] : bf2f(((const ushort_t*)p)[i]);
}

// detect + convert (blocks [0,NCONV)) + wg (blocks [NCONV,NCONV+216)).
__global__ __launch_bounds__(256) void convwg_kernel(
    const void* nf, const void* preW1, const void* preb1, const void* preW2, const void* preb2,
    const void* msgW1, const void* msgb1, const void* msgW2, const void* msgb2,
    const void* gruWih, const void* gruWhh, const void* grubih, const void* grubhh,
    const void* roW1, const void* rob1, const void* roW2, const void* rob2,
    float* __restrict__ w)
{
    __shared__ float w2s[4 * 256];
    __shared__ int cnt;
    const int t = threadIdx.x;
    ushort_t* wb = (ushort_t*)w;

    // ---- inline detect (redundant per block; 4KB L2-hit scan) ----
    if (t == 0) cnt = 0;
    __syncthreads();
    {
        const ushort_t* nf0 = (const ushort_t*)nf;
        int bad = 0;
        for (int i = 0; i < 8; ++i) {
            ushort_t u = nf0[(t * 8 + i) * 2];
            int ex = (u >> 7) & 0xFF;
            if ((u & 0x7fff) != 0 && (ex < 100 || ex > 140)) bad++;
        }
        atomicAdd(&cnt, bad);
    }
    __syncthreads();
    const int f32 = (cnt > 512) ? 1 : 0;

    if (blockIdx.x == 0) {          // publish flag + zero readout counters
        if (t < 4) ((int*)(w + F_GCNT))[t] = 0;
        if (t == 4) *(int*)(w + F_FLAG) = f32;
    }

    if (blockIdx.x < NCONV) {
        const int e0 = (blockIdx.x * 256 + t) * 2;
#pragma unroll
        for (int u2 = 0; u2 < 2; ++u2) {
            int e = e0 + u2;
            if (e >= CV_TOTAL) break;
            if (e < CVa) {                                    // NF
                wb[UB_NFB + e] = f2b(ld(nf, e, f32));
            } else if (e < CVb) {                             // preW1^T [256][64]
                int i = e - CVa; int n = i >> 6, k = i & 63;
                wb[UB_PW1T + i] = f2b(ld(preW1, k * 256 + n, f32));
            } else if (e < CVc) {                             // preW2^T [256][256]
                int i = e - CVb; int n = i >> 8, k = i & 255;
                wb[UB_PW2T + i] = f2b(ld(preW2, k * 256 + n, f32));
            } else if (e < CVd) {                             // Wcat^T [1280][256]
                int i = e - CVc; int n = i >> 8, k = i & 255;
                float v;
                if (n < 256)      v = ld(msgW1, k * 256 + n, f32);
                else if (n < 512) v = ld(msgW1, (256 + k) * 256 + (n - 256), f32);
                else              v = ld(gruWhh, k * 768 + (n - 512), f32);
                wb[UB_WCATT + i] = f2b(v);
            } else {                                          // fp32 tail
                int f = e - CVd;
                float v;
                if (f < 256)        v = ld(preb1, f, f32);
                else if (f < 512)   v = ld(preb2, f - 256, f32);
                else if (f < 1792) {
                    int c = f - 512;
                    if (c < 256)      v = ld(msgb1, c, f32);
                    else if (c < 512) v = 0.f;
                    else              v = ld(grubhh, c - 512, f32);
                }
                else if (f < 2560)  v = ld(grubih, f - 1792, f32);
                else if (f < 68096) v = ld(roW1, f - 2560, f32);
                else if (f < 68352) v = ld(rob1, f - 68096, f32);
                else if (f < 72448) v = ld(roW2, f - 68352, f32);
                else                v = ld(rob2, f - 72448, f32);
                w[F_PREB1 + f] = v;
            }
        }
        return;
    }

    // ---- wg path: Wg[k][p] = sum_n W2hat[k][n]*Wih[n][p] -> WgT[p][576] ----
    const int wt = blockIdx.x - NCONV;   // [0,216)
    const int p0 = (wt % 3) * 256;
    const int k0 = (wt / 3) * 4;
    for (int i = t; i < 4 * 256; i += 256) {
        int r = i >> 8, n = i & 255;
        int krow = k0 + r;
        float v;
        if (krow < 256)       v = ld(msgW2, krow * 256 + n, f32);
        else if (krow == 256) v = ld(msgb2, n, f32);
        else                  v = 0.f;
        w2s[i] = v;
    }
    __syncthreads();
    const int p = p0 + t;
    float acc4[4] = {};
    for (int n0 = 0; n0 < 256; n0 += 32) {
        float wv[32];
#pragma unroll
        for (int i = 0; i < 32; ++i)
            wv[i] = ld(gruWih, (n0 + i) * 768 + p, f32);
#pragma unroll
        for (int r = 0; r < 4; ++r) {
            float acc = acc4[r];
#pragma unroll
            for (int q = 0; q < 8; ++q) {
                f4_t w4 = *(const f4_t*)&w2s[r * 256 + n0 + q * 4];
                acc += w4[0] * wv[q * 4 + 0] + w4[1] * wv[q * 4 + 1]
                     + w4[2] * wv[q * 4 + 2] + w4[3] * wv[q * 4 + 3];
            }
            acc4[r] = acc;
        }
    }
#pragma unroll
    for (int r = 0; r < 4; ++r) {
        int krow = k0 + r;
        ushort_t hi = f2b(acc4[r]);
        ushort_t lo = f2b(acc4[r] - bf2f(hi));
        wb[UB_WGT + p * 576 + krow] = hi;
        wb[UB_WGT + p * 576 + 288 + krow] = lo;
    }
}

// Fused pre-net: X = relu(NF@preW1+b1) (in LDS), h = X@preW2+b2.
// 32 blocks x 32 rows, XCD-pinned: graph g on XCDs {2g,2g+1}.
__global__ __launch_bounds__(256) void prenet_kernel(float* __restrict__ w)
{
    __shared__ ushort_t As[32 * 64];    // NF tile      4KB
    __shared__ ushort_t Xs[32 * 256];   // X tile      16KB
    __shared__ ushort_t Bs[256 * 32];   // weight slab 16KB
    ushort_t* wb = (ushort_t*)w;
    const int t = threadIdx.x;
    const int wave = t >> 6, lane = t & 63;
    const int ln = lane & 15, quad = lane >> 4;
    const int wr = (wave & 1) * 16, wc = (wave >> 1) * 128;
    const int xcd = blockIdx.x & 7;
    const int gph = xcd >> 1;
    const int lidx = ((blockIdx.x >> 3) << 1) | (xcd & 1);   // 0..7
    const int rbase = gph * 256 + lidx * 32;
    const int srow = t >> 2, skc = (t & 3) << 3;

    // stage NF tile [32][64]: 1 bf8 per thread
    {
        int row = t >> 3, kc = (t & 7) << 3;
        *(bf8_t*)(&As[row * 64 + kc]) =
            *(const bf8_t*)(&wb[UB_NFB + (rbase + row) * 64 + kc]);
    }

    f4_t acc[8] = {};
    // phase A: X = relu(NF @ PW1T + b1), K=64
    for (int k0 = 0; k0 < 64; k0 += 32) {
        __syncthreads();
#pragma unroll
        for (int rr = 0; rr < 4; ++rr) {
            int n = srow + 64 * rr;
            *(bf8_t*)(&Bs[n * 32 + skc]) =
                *(const bf8_t*)(&wb[UB_PW1T + n * 64 + k0 + skc]);
        }
        __syncthreads();
        bf8_t af = *(const bf8_t*)(&As[(wr + ln) * 64 + k0 + quad * 8]);
#pragma unroll
        for (int n = 0; n < 8; ++n) {
            bf8_t bfr = *(const bf8_t*)(&Bs[(wc + n * 16 + ln) * 32 + quad * 8]);
            acc[n] = __builtin_amdgcn_mfma_f32_16x16x32_bf16(af, bfr, acc[n], 0, 0, 0);
        }
    }
    __syncthreads();
#pragma unroll
    for (int n = 0; n < 8; ++n) {
        int col = wc + n * 16 + ln;
        float bb = w[F_PREB1 + col];
#pragma unroll
        for (int r = 0; r < 4; ++r) {
            int row = wr + quad * 4 + r;
            Xs[row * 256 + col] = f2b(relu(acc[n][r] + bb));
        }
        acc[n] = (f4_t){0.f, 0.f, 0.f, 0.f};
    }
    __syncthreads();

    // phase B: h = X @ PW2T + b2, K=256
    for (int k0 = 0; k0 < 256; k0 += 32) {
        __syncthreads();
#pragma unroll
        for (int rr = 0; rr < 4; ++rr) {
            int n = srow + 64 * rr;
            *(bf8_t*)(&Bs[n * 32 + skc]) =
                *(const bf8_t*)(&wb[UB_PW2T + n * 256 + k0 + skc]);
        }
        __syncthreads();
        bf8_t af = *(const bf8_t*)(&Xs[(wr + ln) * 256 + k0 + quad * 8]);
#pragma unroll
        for (int n = 0; n < 8; ++n) {
            bf8_t bfr = *(const bf8_t*)(&Bs[(wc + n * 16 + ln) * 32 + quad * 8]);
            acc[n] = __builtin_amdgcn_mfma_f32_16x16x32_bf16(af, bfr, acc[n], 0, 0, 0);
        }
    }
#pragma unroll
    for (int n = 0; n < 8; ++n) {
        int col = wc + n * 16 + ln;
        float bb = w[F_PREB2 + col];
#pragma unroll
        for (int r = 0; r < 4; ++r) {
            int grow = rbase + wr + quad * 4 + r;
            float v = acc[n][r] + bb;
            w[F_H + grow * 256 + col] = v;
            ushort_t hi = f2b(v);
            wb[UB_H2 + grow * 512 + col] = hi;
            wb[UB_H2 + grow * 512 + 256 + col] = f2b(v - bf2f(hi));
        }
    }
}

// hcat GEMM: C[1024,512] = H2[1024,512] @ WcatT[0..512]^T + bias ([hi_p|hj]).
// 32x128 tiles, 128 blocks, XCD-pinned: graph g = bm/256 on XCDs {2g,2g+1}.
// BK=64 (8 rounds), LDS stride 104u, reg-prefetch distance 1.
#define HLD 104
__global__ __launch_bounds__(256) void hcat_kernel(float* __restrict__ w)
{
    __shared__ ushort_t As[32 * HLD];    // 6.6KB
    __shared__ ushort_t Bs[128 * HLD];   // 26.6KB
    ushort_t* wb = (ushort_t*)w;
    const ushort_t* A  = wb + UB_H2;
    const ushort_t* Bt = wb + UB_WCATT;
    const int t = threadIdx.x;
    const int wave = t >> 6, lane = t & 63;
    const int ln = lane & 15, quad = lane >> 4;
    const int xcd = blockIdx.x & 7;
    const int gph = xcd >> 1;
    const int lidx = ((blockIdx.x >> 3) << 1) | (xcd & 1);   // 0..31
    const int bm = gph * 256 + (lidx >> 2) * 32;
    const int bn = (lidx & 3) * 128;
    const int wm = (wave >> 1) * 16, wn = (wave & 1) * 64;

    // staging: A 32 rows x 64u = 256 chunks (1/thread); B 128x64u (4/thread)
    const int arow = t >> 3, akc = (t & 7) << 3;
    const int agoff = (bm + arow) * 512 + akc;
    const int aloff = arow * HLD + akc;
    int bgoff[4], bloff[4];
#pragma unroll
    for (int i = 0; i < 4; ++i) {
        int slot = i * 256 + t;
        int brow = slot >> 3, bkc = (slot & 7) << 3;
        bgoff[i] = (bn + brow) * 256 + bkc;
        bloff[i] = brow * HLD + bkc;
    }

    f4_t acc[4] = {};
    bf8_t ra, rb[4];

    ra = *(const bf8_t*)(&A[agoff]);
#pragma unroll
    for (int i = 0; i < 4; ++i)
        rb[i] = *(const bf8_t*)(&Bt[bgoff[i]]);

    for (int ks = 0; ks < 8; ++ks) {
        __syncthreads();
        *(bf8_t*)(&As[aloff]) = ra;
#pragma unroll
        for (int i = 0; i < 4; ++i)
            *(bf8_t*)(&Bs[bloff[i]]) = rb[i];
        __syncthreads();
        if (ks < 7) {
            int k0 = (ks + 1) * 64;
            int kb = k0 & 255;
            ra = *(const bf8_t*)(&A[agoff + k0]);
#pragma unroll
            for (int i = 0; i < 4; ++i)
                rb[i] = *(const bf8_t*)(&Bt[bgoff[i] + kb]);
        }
#pragma unroll
        for (int kk = 0; kk < 2; ++kk) {
            bf8_t af = *(const bf8_t*)(&As[(wm + ln) * HLD + kk * 32 + quad * 8]);
#pragma unroll
            for (int ni = 0; ni < 4; ++ni) {
                bf8_t bfr = *(const bf8_t*)(&Bs[(wn + ni * 16 + ln) * HLD + kk * 32 + quad * 8]);
                acc[ni] = __builtin_amdgcn_mfma_f32_16x16x32_bf16(af, bfr, acc[ni], 0, 0, 0);
            }
        }
    }

#pragma unroll
    for (int ni = 0; ni < 4; ++ni) {
        int col = bn + wn + ni * 16 + ln;
        float bb = w[F_BCAT + col];
#pragma unroll
        for (int r = 0; r < 4; ++r) {
            int row = bm + wm + quad * 4 + r;
            w[F_HCAT + row * 512 + col] = acc[ni][r] + bb;
        }
    }
}

// Ehat[row] (width 576): [ sum relu(hi_p+hj) hi (256) | deg | 0 | lo (256) | 0 ]
// 1024 blocks, XCD-pinned: row's graph on XCDs {2g,2g+1}.
__global__ __launch_bounds__(256) void msg_kernel(
    const float* __restrict__ hcat,   // [1024][512]: [hi_p | hj]
    const int*   __restrict__ adj,    // [1024][256]
    ushort_t* __restrict__ ehat)      // [1024][576]
{
    const int xcd = blockIdx.x & 7;
    const int gph = xcd >> 1;
    const int idx = ((blockIdx.x >> 3) << 1) | (xcd & 1);  // 0..255
    const int row = gph * 256 + idx;
    const int t = threadIdx.x;
    __shared__ int ej[256];
    __shared__ int ecnt;
    if (t == 0) ecnt = 0;
    __syncthreads();
    if (adj[row * 256 + t]) { int p = atomicAdd(&ecnt, 1); ej[p] = t; }
    const float hi = hcat[row * 512 + t];
    const float* hjb = hcat + gph * 256 * 512 + 256;
    __syncthreads();
    const int ne = ecnt;
    float acc = 0.f;
#pragma unroll 4
    for (int p = 0; p < ne; ++p) {
        int j = ej[p];
        acc += relu(hi + hjb[j * 512 + t]);
    }
    ushort_t h16 = f2b(acc);
    ushort_t l16 = f2b(acc - bf2f(h16));
    ushort_t* er = ehat + row * 576;
    er[t] = h16;
    er[288 + t] = l16;
    if (t < 32) {
        er[256 + t] = f2b(t == 0 ? (float)ne : 0.f);  // deg exact (<=256)
        er[544 + t] = 0;
    }
}

// Fused gi-GEMM + gh-GEMM + GRU, INTERLEAVED super-rounds (R12).
// 256 blocks, XCD-pinned as R11. Phase1: gi = Ehat@Wg (K=864 dedup, BK=96,
// 9 rounds). Phase2: gh = h@Whh (K=512, BK=64, 8 rounds). Super-round sr
// stages+computes p1 round sr AND p2 round sr (sr<8): separate LDS buffers
// and accumulators, per-phase ascending-k MFMA chains unchanged -> bitwise
// identical to R10/R11. 2x loads in flight, 2x compute per stall window,
// 9 stall points instead of 17.  GRU epilogue register-local.
// FINAL: last block per graph (arrival counter to 64) does readout.
#define GLD 104
template<int FINAL>
__global__ __launch_bounds__(256) void gigru_kernel(float* __restrict__ w,
                                                    void* __restrict__ out)
{
    __shared__ ushort_t As1[16 * GLD];    // 3.3KB
    __shared__ ushort_t Bs1[192 * GLD];   // 40KB
    __shared__ ushort_t As2[16 * GLD];    // 3.3KB
    __shared__ ushort_t Bs2[192 * GLD];   // 40KB
    __shared__ float gl[256];
    __shared__ float t1[256];
    __shared__ int donef;
    ushort_t* wb = (ushort_t*)w;
    const int t = threadIdx.x;
    const int wave = t >> 6, lane = t & 63;
    const int ln = lane & 15, quad = lane >> 4;
    const int xcd = blockIdx.x & 7;
    const int gph = xcd >> 1;
    const int lidx = ((blockIdx.x >> 3) << 1) | (xcd & 1);   // 0..63
    const int cg = lidx & 3;
    const int rg = gph * 16 + (lidx >> 2);                   // 0..63
    const int rbase = rg * 16;

    // ---- phase 1 staging geometry (A 16x96, B 192x96; 12 chunks/row) ----
    const int aval = (t < 192);
    const int arow = t / 12, akc = (t % 12) * 8;
    const int agoff = (rbase + arow) * 576 + akc;
    const int aloff = arow * GLD + akc;
    int bgoff[9], bloff[9];
#pragma unroll
    for (int i = 0; i < 9; ++i) {
        int slot = i * 256 + t;
        int brow = slot / 12, bkc = (slot % 12) * 8;
        int wrow = (brow >> 6) * 256 + cg * 64 + (brow & 63);
        bgoff[i] = wrow * 576 + bkc;
        bloff[i] = brow * GLD + bkc;
    }
    const ushort_t* Ehp = wb + UB_EHAT2;
    const ushort_t* Bp  = wb + UB_WGT;

    // ---- phase 2 staging geometry (A 16x64, B 192x64; 8 chunks/row) ----
    const int aval2 = (t < 128);
    const int arow2 = t >> 3, akc2 = (t & 7) << 3;
    const int agoff2 = (rbase + arow2) * 512 + akc2;
    const int aloff2 = arow2 * GLD + akc2;
    int bgoff2[6], bloff2[6];
#pragma unroll
    for (int i = 0; i < 6; ++i) {
        int slot = i * 256 + t;
        int brow = slot >> 3, bkc = (slot & 7) << 3;
        int wrow = 512 + (brow >> 6) * 256 + cg * 64 + (brow & 63);
        bgoff2[i] = wrow * 256 + bkc;
        bloff2[i] = brow * GLD + bkc;
    }
    const ushort_t* Hp = wb + UB_H2;
    const ushort_t* Wp = wb + UB_WCATT;

    f4_t acc[3] = {};      // gi: ir/iz/in
    f4_t acch[3] = {};     // gh: hr/hz/hn
    bf8_t ra1, rb1[9], ra2, rb2[6];

    // prologue: load both phases' round 0
    if (aval) ra1 = *(const bf8_t*)(&Ehp[agoff]);
#pragma unroll
    for (int i = 0; i < 9; ++i)
        rb1[i] = *(const bf8_t*)(&Bp[bgoff[i]]);
    if (aval2) ra2 = *(const bf8_t*)(&Hp[agoff2]);
#pragma unroll
    for (int i = 0; i < 6; ++i)
        rb2[i] = *(const bf8_t*)(&Wp[bgoff2[i]]);

    for (int sr = 0; sr < 9; ++sr) {
        __syncthreads();
        // write LDS for this super-round
        if (aval) *(bf8_t*)(&As1[aloff]) = ra1;
#pragma unroll
        for (int i = 0; i < 9; ++i)
            *(bf8_t*)(&Bs1[bloff[i]]) = rb1[i];
        if (sr < 8) {
            if (aval2) *(bf8_t*)(&As2[aloff2]) = ra2;
#pragma unroll
            for (int i = 0; i < 6; ++i)
                *(bf8_t*)(&Bs2[bloff2[i]]) = rb2[i];
        }
        __syncthreads();
        // issue next round's loads (20 in flight)
        if (sr < 8) {
            int k0 = (sr + 1) * 96;
            int ka = (k0 < 576) ? k0 : k0 - 576;   // A: Eh reused
            int kb = (k0 < 288) ? k0 : k0 - 288;   // B: hi reused
            if (aval) ra1 = *(const bf8_t*)(&Ehp[agoff + ka]);
#pragma unroll
            for (int i = 0; i < 9; ++i)
                rb1[i] = *(const bf8_t*)(&Bp[bgoff[i] + kb]);
        }
        if (sr < 7) {
            int k0 = (sr + 1) * 64;
            int kb = k0 & 255;                     // B dedup
            if (aval2) ra2 = *(const bf8_t*)(&Hp[agoff2 + k0]);
#pragma unroll
            for (int i = 0; i < 6; ++i)
                rb2[i] = *(const bf8_t*)(&Wp[bgoff2[i] + kb]);
        }
        // compute phase 1 round sr (k ascending within round -> chain order
        // identical to the non-interleaved version)
#pragma unroll
        for (int kk = 0; kk < 3; ++kk) {
            bf8_t af = *(const bf8_t*)(&As1[ln * GLD + kk * 32 + quad * 8]);
#pragma unroll
            for (int n = 0; n < 3; ++n) {
                int fn = wave + n * 4;
                bf8_t bfr = *(const bf8_t*)(&Bs1[(fn * 16 + ln) * GLD + kk * 32 + quad * 8]);
                acc[n] = __builtin_amdgcn_mfma_f32_16x16x32_bf16(af, bfr, acc[n], 0, 0, 0);
            }
        }
        // compute phase 2 round sr
        if (sr < 8) {
#pragma unroll
            for (int kk = 0; kk < 2; ++kk) {
                bf8_t af = *(const bf8_t*)(&As2[ln * GLD + kk * 32 + quad * 8]);
#pragma unroll
                for (int n = 0; n < 3; ++n) {
                    int fn = wave + n * 4;
                    bf8_t bfr = *(const bf8_t*)(&Bs2[(fn * 16 + ln) * GLD + kk * 32 + quad * 8]);
                    acch[n] = __builtin_amdgcn_mfma_f32_16x16x32_bf16(af, bfr, acch[n], 0, 0, 0);
                }
            }
        }
    }

    // GRU epilogue: acc=ir/iz/in + bih; acch=hr/hz/hn + bhh. Register-local.
    {
        const int col = cg * 64 + wave * 16 + ln;
        float bi_r = w[F_BIH + col];
        float bi_z = w[F_BIH + 256 + col];
        float bi_n = w[F_BIH + 512 + col];
        float bh_r = w[F_BCAT + 512 + col];
        float bh_z = w[F_BCAT + 768 + col];
        float bh_n = w[F_BCAT + 1024 + col];
#pragma unroll
        for (int r = 0; r < 4; ++r) {
            int row = rbase + quad * 4 + r;
            float ir = acc[0][r] + bi_r;
            float iz = acc[1][r] + bi_z;
            float in = acc[2][r] + bi_n;
            float hr = acch[0][r] + bh_r;
            float hz = acch[1][r] + bh_z;
            float hn = acch[2][r] + bh_n;
            float rg_ = 1.f / (1.f + __expf(-(ir + hr)));
            float z   = 1.f / (1.f + __expf(-(iz + hz)));
            float nn  = tanhf(in + rg_ * hn);
            float ho = w[F_H + row * 256 + col];
            float hv = (1.f - z) * nn + z * ho;
            w[F_H + row * 256 + col] = hv;
            if (!FINAL) {
                ushort_t hb = f2b(hv);
                wb[UB_H2 + row * 512 + col] = hb;
                wb[UB_H2 + row * 512 + 256 + col] = f2b(hv - bf2f(hb));
            }
        }
    }

    if (FINAL) {
        // per-graph arrival counter: 64 blocks/graph; last one does readout.
        const int g = gph;
        __syncthreads();
        if (t == 0) {
            __threadfence();                           // release h writes
            int prev = atomicAdd((int*)(w + F_GCNT) + g, 1);
            donef = (prev == 63);
        }
        __syncthreads();
        if (!donef) return;
        __threadfence();                               // acquire others' h

        const float* hb = w + F_H + g * 256 * 256;
        float s = 0.f;
        for (int n = 0; n < 256; ++n) s += hb[n * 256 + t];
        gl[t] = s;
        __syncthreads();
        float acc1 = w[F_ROB1 + t];
        for (int k = 0; k < 256; ++k) acc1 += gl[k] * w[F_ROW1 + k * 256 + t];
        t1[t] = relu(acc1);
        __syncthreads();
        if (t < 16) {
            float q = w[F_ROB2 + t];
            for (int k = 0; k < 256; ++k) q += t1[k] * w[F_ROW2 + k * 16 + t];
            if (*(const int*)(w + F_FLAG)) ((float*)out)[g * 16 + t] = q;
            else ((__hip_bfloat16*)out)[g * 16 + t] = __float2bfloat16(q);
        }
    }
}

extern "C" void kernel_launch(void* const* d_in, const int* in_sizes, int n_in,
                              void* d_out, int out_size, void* d_ws, size_t ws_size,
                              hipStream_t stream) {
    float* w = (float*)d_ws;
    ushort_t* wb = (ushort_t*)d_ws;

    static const int dictSz[18]  = {65536,262144,16384,256,65536,256,131072,256,65536,256,
                                    196608,196608,768,768,65536,256,4096,16};
    static const int alphaSz[18] = {262144,196608,196608,768,768,131072,65536,256,256,
                                    65536,16384,65536,256,256,65536,4096,256,16};
    static const int alphaPos[18] = {9,0,10,12,11,13,5,7,6,8,2,1,4,3,14,16,15,17};
    bool dictOK = true, alphaOK = true;
    for (int i = 0; i < 18 && i < n_in; ++i) {
        if (in_sizes[i] != dictSz[i])  dictOK = false;
        if (in_sizes[i] != alphaSz[i]) alphaOK = false;
    }
    const void* P[18];
    for (int l = 0; l < 18; ++l) P[l] = d_in[(!dictOK && alphaOK) ? alphaPos[l] : l];
    const int* adj = (const int*)P[1];

    convwg_kernel<<<NCONV + 216, 256, 0, stream>>>(
        P[0], P[2], P[3], P[4], P[5], P[6], P[7], P[8], P[9],
        P[10], P[11], P[12], P[13], P[14], P[15], P[16], P[17], w);

    prenet_kernel<<<32, 256, 0, stream>>>(w);

    for (int it = 0; it < 3; ++it) {
        hcat_kernel<<<128, 256, 0, stream>>>(w);
        msg_kernel<<<BN_ROWS, 256, 0, stream>>>(w + F_HCAT, adj, wb + UB_EHAT2);
        if (it < 2)
            gigru_kernel<0><<<256, 256, 0, stream>>>(w, d_out);
        else
            gigru_kernel<1><<<256, 256, 0, stream>>>(w, d_out);
    }
}